// Round 12
// baseline (2142.241 us; speedup 1.0000x reference)
//
#include <hip/hip_runtime.h>
#include <hip/hip_bf16.h>

#define NN 100000
#define NE 1000000
#define DD 128
#define KCAT 1152              // 9*128 (8 relations + root)

typedef short bf16x8 __attribute__((ext_vector_type(8)));
typedef float f32x4 __attribute__((ext_vector_type(4)));

__device__ __forceinline__ unsigned short f2bf(float f) {
    union { float f; unsigned int u; } c; c.f = f;
    unsigned int u = c.u;
    u += 0x7fffu + ((u >> 16) & 1u);    // round-to-nearest-even
    return (unsigned short)(u >> 16);
}

// fp32 -> bf16, 4 elems/thread
__global__ __launch_bounds__(256) void cvt_x_k(const float* __restrict__ in,
                                               unsigned short* __restrict__ out,
                                               int n4) {
    int i = blockIdx.x * 256 + threadIdx.x;
    if (i >= n4) return;
    float4 v = reinterpret_cast<const float4*>(in)[i];
    ushort4 o;
    o.x = f2bf(v.x); o.y = f2bf(v.y); o.z = f2bf(v.z); o.w = f2bf(v.w);
    reinterpret_cast<ushort4*>(out)[i] = o;
}

// Build Wcat[e][m*128+d] = W[m][d][e] (m<8) / root[d][e] (m==8), bf16, both layers.
__global__ __launch_bounds__(256) void cvt_w_k(const float* __restrict__ W1,
                                               const float* __restrict__ r1,
                                               const float* __restrict__ W2,
                                               const float* __restrict__ r2,
                                               unsigned short* __restrict__ wc1,
                                               unsigned short* __restrict__ wc2) {
    int idx = blockIdx.x * 256 + threadIdx.x;       // 0 .. 2*128*1152-1
    int l   = idx / (DD * KCAT);
    int rem = idx % (DD * KCAT);
    int e   = rem / KCAT;
    int md  = rem % KCAT;
    int m = md / DD, d = md % DD;
    const float* W = (l == 0) ? W1 : W2;
    const float* rt = (l == 0) ? r1 : r2;
    float v = (m < 8) ? W[(size_t)m * DD * DD + (size_t)d * DD + e]
                      : rt[(size_t)d * DD + e];
    ((l == 0) ? wc1 : wc2)[rem] = f2bf(v);
}

// per-(dst,r) degree + per-src out-degree (posS doubles as count)
__global__ __launch_bounds__(256) void hist_k(const int* __restrict__ src,
                                              const int* __restrict__ dst,
                                              const int* __restrict__ et,
                                              unsigned int* __restrict__ deg8,
                                              unsigned int* __restrict__ posS) {
    int e = blockIdx.x * 256 + threadIdx.x;
    if (e >= NE) return;
    atomicAdd(&deg8[(size_t)dst[e] * 8 + et[e]], 1u);
    atomicAdd(&posS[src[e]], 1u);
}

// Per node: dst-side (d,r)-grouped slot alloc (chunked by node half) and
// src-side offsets (in-place count -> base).
__global__ __launch_bounds__(256) void offs_k(const unsigned int* __restrict__ deg8,
                                              unsigned int* __restrict__ cnts,
                                              unsigned int* __restrict__ pos8,
                                              unsigned int* __restrict__ posS,
                                              unsigned int* __restrict__ segBeg,
                                              unsigned int* __restrict__ segLen,
                                              unsigned int CAP, int nch) {
    int node = blockIdx.x * 256 + threadIdx.x;
    if (node >= NN) return;
    const uint4* dp = reinterpret_cast<const uint4*>(&deg8[(size_t)node * 8]);
    uint4 a = dp[0], b = dp[1];
    unsigned int tot = a.x + a.y + a.z + a.w + b.x + b.y + b.z + b.w;
    int c = (nch == 2 && node >= NN / 2) ? 1 : 0;
    unsigned int base = atomicAdd(&cnts[c], tot) + (unsigned int)c * CAP;
    unsigned int* pp = &pos8[(size_t)node * 8];
    unsigned int run = base;
    pp[0] = run; run += a.x;  pp[1] = run; run += a.y;
    pp[2] = run; run += a.z;  pp[3] = run; run += a.w;
    pp[4] = run; run += b.x;  pp[5] = run; run += b.y;
    pp[6] = run; run += b.z;  pp[7] = run; run += b.w;
    segBeg[node] = base;
    segLen[node] = tot;
    // src side: count -> base
    unsigned int q0 = atomicAdd(&cnts[2], posS[node]);
    posS[node] = q0;
}

// Per edge: assign dst-slot p ((d,r)-grouped) and src-sorted position q.
// recD[p] = r; recA[q] = src | deg<<17; recB[q] = p.
__global__ __launch_bounds__(256) void fill_k(const int* __restrict__ src,
                                              const int* __restrict__ dst,
                                              const int* __restrict__ et,
                                              const unsigned int* __restrict__ deg8,
                                              unsigned int* __restrict__ pos8,
                                              unsigned int* __restrict__ posS,
                                              unsigned int* __restrict__ recA,
                                              unsigned int* __restrict__ recB,
                                              unsigned char* __restrict__ recD) {
    int e = blockIdx.x * 256 + threadIdx.x;
    if (e >= NE) return;
    int s = src[e], d = dst[e], r = et[e];
    unsigned int p = atomicAdd(&pos8[(size_t)d * 8 + r], 1u);
    recD[p] = (unsigned char)r;
    unsigned int q = atomicAdd(&posS[s], 1u);
    unsigned int dg = deg8[(size_t)d * 8 + r];
    if (dg > 2047u) dg = 2047u;
    recA[q] = (unsigned int)s | (dg << 17);
    recB[q] = p;
}

// Spread: walk edges in src-sorted order (x-row L1 reuse), pre-scale by
// rcp(deg), write 256B row to its dst-sorted slot (non-temporal).
// 625 blocks x 512 thr = 5000 waves x 200 edges (exact).
__global__ __launch_bounds__(512) void spread_k(const unsigned short* __restrict__ xb,
                                                const unsigned int* __restrict__ recA,
                                                const unsigned int* __restrict__ recB,
                                                unsigned short* __restrict__ y,
                                                unsigned int chunkOff, unsigned int CAP) {
    const int gw   = blockIdx.x * 8 + (threadIdx.x >> 6);   // 0..4999
    const int lane = threadIdx.x & 63;
    const int b0   = gw * 200;

    for (int b = 0; b < 200; b += 8) {
        int j = b0 + b;                                     // multiple of 8
        uint4 a0 = *reinterpret_cast<const uint4*>(recA + j);
        uint4 a1 = *reinterpret_cast<const uint4*>(recA + j + 4);
        uint4 s0 = *reinterpret_cast<const uint4*>(recB + j);
        uint4 s1 = *reinterpret_cast<const uint4*>(recB + j + 4);
        unsigned int pk[8] = {a0.x, a0.y, a0.z, a0.w, a1.x, a1.y, a1.z, a1.w};
        unsigned int sl[8] = {s0.x, s0.y, s0.z, s0.w, s1.x, s1.y, s1.z, s1.w};
        unsigned int hv[8];
#pragma unroll
        for (int u = 0; u < 8; ++u) {
            unsigned int rel = sl[u] - chunkOff;
            if (rel < CAP)
                hv[u] = *reinterpret_cast<const unsigned int*>(
                    xb + (size_t)(pk[u] & 0x1FFFFu) * DD + lane * 2);
        }
#pragma unroll
        for (int u = 0; u < 8; ++u) {
            unsigned int rel = sl[u] - chunkOff;
            if (rel < CAP) {
                float sc = __builtin_amdgcn_rcpf((float)(pk[u] >> 17));
                union { unsigned int u32; float f; } lo, hi;
                lo.u32 = hv[u] << 16; hi.u32 = hv[u] & 0xffff0000u;
                float flo = lo.f * sc, fhi = hi.f * sc;
                unsigned int w32;
                asm volatile("v_cvt_pk_bf16_f32 %0, %1, %2"
                             : "=v"(w32) : "v"(flo), "v"(fhi));
                __builtin_nontemporal_store(w32,
                    reinterpret_cast<unsigned int*>(y + (size_t)rel * DD + lane * 2));
            }
        }
    }
}

// Aggregate layer: block = 512 thr = 8 waves = 16 dst nodes (2/wave).
// Phase 1: sequential y-segment read, run-flush per relation (sum; scale was
//          pre-applied) into swizzled bf16 LDS; root x at slice 8.
// Phase 2: out[16][128] = xagg @ Wcat^T via MFMA, +bias, relu.
// mode 1: bf16 store (next layer input); mode 2: f32 store (final output).
__global__ __launch_bounds__(512) void agg_k(const unsigned short* __restrict__ xb,
                                             const unsigned short* __restrict__ wcat,
                                             const float* __restrict__ bias,
                                             const unsigned char* __restrict__ recD,
                                             const unsigned int* __restrict__ segBeg,
                                             const unsigned int* __restrict__ segLen,
                                             const unsigned short* __restrict__ y,
                                             unsigned int chunkOff, int nodeLo,
                                             unsigned short* __restrict__ obf,
                                             float* __restrict__ of32,
                                             int mode) {
    __shared__ unsigned short ldsx[16 * KCAT];      // 36,864 B
    const int wave = threadIdx.x >> 6;              // 0..7
    const int lane = threadIdx.x & 63;
    const int c16  = lane & 15;
    const int grp  = lane >> 4;
    const int lq   = lane >> 2;
    const int lm   = lane & 3;
    const int blk  = blockIdx.x;
    unsigned int* lds32 = reinterpret_cast<unsigned int*>(ldsx);

    // ---------- phase 1: sequential segment read + run-flush ----------
    for (int nl = 0; nl < 2; ++nl) {
        const int row  = wave * 2 + nl;             // LDS row 0..15
        const int node = nodeLo + blk * 16 + row;
        const int sbase = row * (KCAT / 2);         // u32 units per row
        const int xorv = row & 7;

        // zero relation slices; write root slice (m=8)
#pragma unroll
        for (int r = 0; r < 8; ++r)
            lds32[sbase + (((r * 16 + lq) ^ xorv) << 2) + lm] = 0u;
        lds32[sbase + (((128 + lq) ^ xorv) << 2) + lm] =
            *reinterpret_cast<const unsigned int*>(xb + (size_t)node * DD + lane * 2);

        const unsigned int beg = segBeg[node];
        const unsigned int len = segLen[node];
        const unsigned char* rp = recD + beg;
        const unsigned short* yb = y + (size_t)(beg - chunkOff) * DD;

        float ax = 0.f, ay = 0.f;
        unsigned int rc = 15u;
        for (unsigned int j = 0; j < len; j += 8) {
            int n = (int)(len - j); if (n > 8) n = 8;
            unsigned int hv[8]; unsigned char rr[8];
#pragma unroll
            for (int u = 0; u < 8; ++u)
                if (u < n) {
                    rr[u] = rp[j + u];
                    hv[u] = *reinterpret_cast<const unsigned int*>(
                        yb + (size_t)(j + u) * DD + lane * 2);
                }
#pragma unroll
            for (int u = 0; u < 8; ++u)
                if (u < n) {
                    unsigned int r = rr[u];
                    if (r != rc) {
                        if (rc < 8u) {
                            unsigned int w32 = ((unsigned int)f2bf(ay) << 16)
                                             | (unsigned int)f2bf(ax);
                            lds32[sbase + ((((int)rc * 16 + lq) ^ xorv) << 2) + lm] = w32;
                        }
                        rc = r; ax = 0.f; ay = 0.f;
                    }
                    union { unsigned int u32; float f; } lo, hi;
                    lo.u32 = hv[u] << 16; hi.u32 = hv[u] & 0xffff0000u;
                    ax += lo.f; ay += hi.f;
                }
        }
        if (rc < 8u) {
            unsigned int w32 = ((unsigned int)f2bf(ay) << 16)
                             | (unsigned int)f2bf(ax);
            lds32[sbase + ((((int)rc * 16 + lq) ^ xorv) << 2) + lm] = w32;
        }
    }
    __syncthreads();

    // ---------- phase 2: MFMA out = xagg @ Wcat^T (wave w -> col tile w) ----------
    f32x4 acc = f32x4{0.f, 0.f, 0.f, 0.f};
    const unsigned short* arow = wcat + (size_t)(wave * 16 + c16) * KCAT;
#pragma unroll
    for (int kk = 0; kk < KCAT / 32; ++kk) {        // 36 k-steps
        int slot = (kk * 4 + grp) ^ (c16 & 7);
        bf16x8 b = *reinterpret_cast<const bf16x8*>(&ldsx[c16 * KCAT + slot * 8]);
        bf16x8 a = *reinterpret_cast<const bf16x8*>(arow + kk * 32 + grp * 8);
        acc = __builtin_amdgcn_mfma_f32_16x16x32_bf16(a, b, acc, 0, 0, 0);
    }

    // ---------- epilogue: +bias, relu, store ----------
    const int node = nodeLo + blk * 16 + c16;
    const int od = wave * 16 + grp * 4;
    const float4 bv = *reinterpret_cast<const float4*>(bias + od);
    float o0 = fmaxf(acc[0] + bv.x, 0.f);
    float o1 = fmaxf(acc[1] + bv.y, 0.f);
    float o2 = fmaxf(acc[2] + bv.z, 0.f);
    float o3 = fmaxf(acc[3] + bv.w, 0.f);
    if (mode == 1) {
        union { unsigned short s[4]; uint2 v; } pko;
        pko.s[0] = f2bf(o0); pko.s[1] = f2bf(o1);
        pko.s[2] = f2bf(o2); pko.s[3] = f2bf(o3);
        *reinterpret_cast<uint2*>(obf + (size_t)node * DD + od) = pko.v;
    } else {
        *reinterpret_cast<float4*>(of32 + (size_t)node * DD + od)
            = make_float4(o0, o1, o2, o3);
    }
}

extern "C" void kernel_launch(void* const* d_in, const int* in_sizes, int n_in,
                              void* d_out, int out_size, void* d_ws, size_t ws_size,
                              hipStream_t stream) {
    const float* x  = (const float*)d_in[0];
    const int*   ei = (const int*)d_in[1];
    const int*   et = (const int*)d_in[2];
    const float* W1 = (const float*)d_in[3];
    const float* r1 = (const float*)d_in[4];
    const float* b1 = (const float*)d_in[5];
    const float* W2 = (const float*)d_in[6];
    const float* r2 = (const float*)d_in[7];
    const float* b2 = (const float*)d_in[8];
    float* out = (float*)d_out;

    // ---- fixed workspace layout (~67.5 MB) ----
    char* ws = (char*)d_ws;
    unsigned int*   deg8   = (unsigned int*)ws;                   // NN*8 u32
    unsigned int*   cnts   = deg8 + (size_t)NN * 8;               // 64 u32
    unsigned int*   posS   = cnts + 64;                           // NN u32
    unsigned int*   pos8   = posS + NN;                           // NN*8 u32
    unsigned int*   segBeg = pos8 + (size_t)NN * 8;               // NN u32
    unsigned int*   segLen = segBeg + NN;                         // NN u32
    unsigned int*   recA   = segLen + NN;                         // NE u32
    unsigned int*   recB   = recA + NE;                           // NE u32
    unsigned short* wc1    = (unsigned short*)(recB + NE);        // 294,912 B
    unsigned short* wc2    = wc1 + DD * KCAT;
    unsigned short* xbuf   = wc2 + DD * KCAT;                     // 25.6 MB
    unsigned short* xbuf2  = xbuf + (size_t)NN * DD;              // 25.6 MB
    size_t fixedEnd = (size_t)((char*)(xbuf2 + (size_t)NN * DD) - ws);
    fixedEnd = (fixedEnd + 255) & ~(size_t)255;

    // ---- adaptive y / recD sizing ----
    if (ws_size < fixedEnd + 1024) return;
    size_t avail = ws_size - fixedEnd - 512;
    int nch; unsigned int CAP;
    if (avail >= (size_t)NE * 257) { nch = 1; CAP = NE; }
    else {
        nch = 2;
        CAP = (unsigned int)(avail / 258);
        if (CAP < 530000u) return;                  // loud failure
        if (CAP > NE) CAP = NE;
    }
    unsigned char* recD = (unsigned char*)(ws + fixedEnd);        // nch*CAP B
    size_t yOff = (fixedEnd + (size_t)nch * CAP + 255) & ~(size_t)255;
    unsigned short* y = (unsigned short*)(ws + yOff);             // CAP*256 B

    const int* srcv = ei;
    const int* dstv = ei + NE;

    hipMemsetAsync(deg8, 0, (size_t)NN * 8 * 4 + 256 + (size_t)NN * 4, stream);
    cvt_x_k<<<(NN * DD / 4) / 256, 256, 0, stream>>>(x, xbuf, NN * DD / 4);
    cvt_w_k<<<(2 * DD * KCAT) / 256, 256, 0, stream>>>(W1, r1, W2, r2, wc1, wc2);
    hist_k<<<(NE + 255) / 256, 256, 0, stream>>>(srcv, dstv, et, deg8, posS);
    offs_k<<<(NN + 255) / 256, 256, 0, stream>>>(deg8, cnts, pos8, posS,
                                                 segBeg, segLen, CAP, nch);
    fill_k<<<(NE + 255) / 256, 256, 0, stream>>>(srcv, dstv, et, deg8, pos8, posS,
                                                 recA, recB, recD);

    const int nodesPer = NN / nch;                  // 100000 or 50000
    const int aggBlocks = nodesPer / 16;            // 6250 or 3125
    for (int layer = 0; layer < 2; ++layer) {
        const unsigned short* in = layer ? xbuf2 : xbuf;
        const unsigned short* wc = layer ? wc2 : wc1;
        const float* bb = layer ? b2 : b1;
        for (int c = 0; c < nch; ++c) {
            unsigned int chunkOff = (unsigned int)c * CAP;
            spread_k<<<625, 512, 0, stream>>>(in, recA, recB, y, chunkOff, CAP);
            agg_k<<<aggBlocks, 512, 0, stream>>>(in, wc, bb, recD, segBeg, segLen,
                                                 y, chunkOff, c * nodesPer,
                                                 layer ? (unsigned short*)nullptr : xbuf2,
                                                 layer ? out : (float*)nullptr,
                                                 layer ? 2 : 1);
        }
    }
}

// Round 13
// 984.316 us; speedup vs baseline: 2.1764x; 2.1764x over previous
//
#include <hip/hip_runtime.h>
#include <hip/hip_bf16.h>

#define NN 100000
#define NE 1000000
#define DD 128
#define KCAT 1152              // 9*128 (8 relations + root)
#define SCAN_BLKS 391          // ceil(NN/256)
#define CHB 50176              // chunk boundary: 196*256 (multiple of 256 and 16)

typedef short bf16x8 __attribute__((ext_vector_type(8)));
typedef float f32x4 __attribute__((ext_vector_type(4)));

__device__ __forceinline__ unsigned short f2bf(float f) {
    union { float f; unsigned int u; } c; c.f = f;
    unsigned int u = c.u;
    u += 0x7fffu + ((u >> 16) & 1u);    // round-to-nearest-even
    return (unsigned short)(u >> 16);
}

// fp32 -> bf16, 4 elems/thread
__global__ __launch_bounds__(256) void cvt_x_k(const float* __restrict__ in,
                                               unsigned short* __restrict__ out,
                                               int n4) {
    int i = blockIdx.x * 256 + threadIdx.x;
    if (i >= n4) return;
    float4 v = reinterpret_cast<const float4*>(in)[i];
    ushort4 o;
    o.x = f2bf(v.x); o.y = f2bf(v.y); o.z = f2bf(v.z); o.w = f2bf(v.w);
    reinterpret_cast<ushort4*>(out)[i] = o;
}

// Build Wcat[e][m*128+d] = W[m][d][e] (m<8) / root[d][e] (m==8), bf16, both layers.
__global__ __launch_bounds__(256) void cvt_w_k(const float* __restrict__ W1,
                                               const float* __restrict__ r1,
                                               const float* __restrict__ W2,
                                               const float* __restrict__ r2,
                                               unsigned short* __restrict__ wc1,
                                               unsigned short* __restrict__ wc2) {
    int idx = blockIdx.x * 256 + threadIdx.x;       // 0 .. 2*128*1152-1
    int l   = idx / (DD * KCAT);
    int rem = idx % (DD * KCAT);
    int e   = rem / KCAT;
    int md  = rem % KCAT;
    int m = md / DD, d = md % DD;
    const float* W = (l == 0) ? W1 : W2;
    const float* rt = (l == 0) ? r1 : r2;
    float v = (m < 8) ? W[(size_t)m * DD * DD + (size_t)d * DD + e]
                      : rt[(size_t)d * DD + e];
    ((l == 0) ? wc1 : wc2)[rem] = f2bf(v);
}

// per-(dst,r) degree + per-src out-degree
__global__ __launch_bounds__(256) void hist_k(const int* __restrict__ src,
                                              const int* __restrict__ dst,
                                              const int* __restrict__ et,
                                              unsigned int* __restrict__ deg8,
                                              unsigned int* __restrict__ srcCnt) {
    int e = blockIdx.x * 256 + threadIdx.x;
    if (e >= NE) return;
    atomicAdd(&deg8[(size_t)dst[e] * 8 + et[e]], 1u);
    atomicAdd(&srcCnt[src[e]], 1u);
}

// scan stage A: per-block (256 nodes) exclusive scans of dst-tot and src-cnt
__global__ __launch_bounds__(256) void scanA_k(const unsigned int* __restrict__ deg8,
                                               const unsigned int* __restrict__ srcCnt,
                                               unsigned int* __restrict__ locD,
                                               unsigned int* __restrict__ locS,
                                               unsigned int* __restrict__ blkD,
                                               unsigned int* __restrict__ blkS) {
    __shared__ unsigned int sD[256], sS[256];
    const int t = threadIdx.x;
    const int node = blockIdx.x * 256 + t;
    unsigned int dtot = 0, stot = 0;
    if (node < NN) {
        const uint4* dp = reinterpret_cast<const uint4*>(&deg8[(size_t)node * 8]);
        uint4 a = dp[0], b = dp[1];
        dtot = a.x + a.y + a.z + a.w + b.x + b.y + b.z + b.w;
        stot = srcCnt[node];
    }
    sD[t] = dtot; sS[t] = stot;
    __syncthreads();
    for (int off = 1; off < 256; off <<= 1) {
        unsigned int vD = (t >= off) ? sD[t - off] : 0u;
        unsigned int vS = (t >= off) ? sS[t - off] : 0u;
        __syncthreads();
        sD[t] += vD; sS[t] += vS;
        __syncthreads();
    }
    if (node < NN) { locD[node] = sD[t] - dtot; locS[node] = sS[t] - stot; }
    if (t == 255) { blkD[blockIdx.x] = sD[255]; blkS[blockIdx.x] = sS[255]; }
}

// scan stage B: single block scans the 391 block sums; computes chunk offsets
__global__ __launch_bounds__(512) void scanB_k(unsigned int* __restrict__ blkD,
                                               unsigned int* __restrict__ blkS,
                                               unsigned int* __restrict__ cOff,
                                               int nch) {
    __shared__ unsigned int sD[512], sS[512];
    const int t = threadIdx.x;
    unsigned int vD = (t < SCAN_BLKS) ? blkD[t] : 0u;
    unsigned int vS = (t < SCAN_BLKS) ? blkS[t] : 0u;
    sD[t] = vD; sS[t] = vS;
    __syncthreads();
    for (int off = 1; off < 512; off <<= 1) {
        unsigned int aD = (t >= off) ? sD[t - off] : 0u;
        unsigned int aS = (t >= off) ? sS[t - off] : 0u;
        __syncthreads();
        sD[t] += aD; sS[t] += aS;
        __syncthreads();
    }
    if (t < SCAN_BLKS) { blkD[t] = sD[t] - vD; blkS[t] = sS[t] - vS; }
    if (t == 0) cOff[0] = 0u;
    if (t == 196 && nch == 2) cOff[1] = sD[196] - vD;   // records of nodes [0, CHB)
    if (t == SCAN_BLKS - 1) {
        unsigned int tot = sD[t];
        cOff[2] = tot;
        if (nch == 1) cOff[1] = tot;
    }
}

// scan stage C: distribute bases -> segBeg/segLen, per-(node,r) pos8, src posS
__global__ __launch_bounds__(256) void scanC_k(const unsigned int* __restrict__ deg8,
                                               const unsigned int* __restrict__ locD,
                                               const unsigned int* __restrict__ locS,
                                               const unsigned int* __restrict__ blkD,
                                               const unsigned int* __restrict__ blkS,
                                               unsigned int* __restrict__ pos8,
                                               unsigned int* __restrict__ posS,
                                               unsigned int* __restrict__ segBeg,
                                               unsigned int* __restrict__ segLen) {
    const int node = blockIdx.x * 256 + threadIdx.x;
    if (node >= NN) return;
    const uint4* dp = reinterpret_cast<const uint4*>(&deg8[(size_t)node * 8]);
    uint4 a = dp[0], b = dp[1];
    unsigned int base = blkD[blockIdx.x] + locD[node];
    unsigned int* pp = &pos8[(size_t)node * 8];
    unsigned int run = base;
    pp[0] = run; run += a.x;  pp[1] = run; run += a.y;
    pp[2] = run; run += a.z;  pp[3] = run; run += a.w;
    pp[4] = run; run += b.x;  pp[5] = run; run += b.y;
    pp[6] = run; run += b.z;  pp[7] = run; run += b.w;
    segBeg[node] = base;
    segLen[node] = run - base;
    posS[node] = blkS[blockIdx.x] + locS[node];
}

// Per edge: assign dst-slot p ((d,r)-grouped, node-ordered) and src-sorted pos q.
// recD[p] = r; recA[q] = src | deg<<17; recB[q] = p.
__global__ __launch_bounds__(256) void fill_k(const int* __restrict__ src,
                                              const int* __restrict__ dst,
                                              const int* __restrict__ et,
                                              const unsigned int* __restrict__ deg8,
                                              unsigned int* __restrict__ pos8,
                                              unsigned int* __restrict__ posS,
                                              unsigned int* __restrict__ recA,
                                              unsigned int* __restrict__ recB,
                                              unsigned char* __restrict__ recD) {
    int e = blockIdx.x * 256 + threadIdx.x;
    if (e >= NE) return;
    int s = src[e], d = dst[e], r = et[e];
    unsigned int p = atomicAdd(&pos8[(size_t)d * 8 + r], 1u);
    recD[p] = (unsigned char)r;
    unsigned int q = atomicAdd(&posS[s], 1u);
    unsigned int dg = deg8[(size_t)d * 8 + r];
    if (dg > 2047u) dg = 2047u;
    recA[q] = (unsigned int)s | (dg << 17);
    recB[q] = p;
}

// Spread: walk edges in src-sorted order (x-row L1/L2 reuse), pre-scale by
// rcp(deg), write 256B row to its dst-sorted slot (non-temporal).
// 625 blocks x 512 thr = 5000 waves x 200 edges (exact).
__global__ __launch_bounds__(512) void spread_k(const unsigned short* __restrict__ xb,
                                                const unsigned int* __restrict__ recA,
                                                const unsigned int* __restrict__ recB,
                                                unsigned short* __restrict__ y,
                                                const unsigned int* __restrict__ cOff,
                                                int c) {
    const unsigned int lo = cOff[c];
    const unsigned int hi = cOff[c + 1];
    const int gw   = blockIdx.x * 8 + (threadIdx.x >> 6);   // 0..4999
    const int lane = threadIdx.x & 63;
    const int b0   = gw * 200;

    for (int b = 0; b < 200; b += 8) {
        int j = b0 + b;                                     // multiple of 8
        uint4 a0 = *reinterpret_cast<const uint4*>(recA + j);
        uint4 a1 = *reinterpret_cast<const uint4*>(recA + j + 4);
        uint4 s0 = *reinterpret_cast<const uint4*>(recB + j);
        uint4 s1 = *reinterpret_cast<const uint4*>(recB + j + 4);
        unsigned int pk[8] = {a0.x, a0.y, a0.z, a0.w, a1.x, a1.y, a1.z, a1.w};
        unsigned int sl[8] = {s0.x, s0.y, s0.z, s0.w, s1.x, s1.y, s1.z, s1.w};
        unsigned int hv[8];
#pragma unroll
        for (int u = 0; u < 8; ++u) {
            unsigned int rel = sl[u] - lo;                  // wave-uniform
            if (sl[u] >= lo && sl[u] < hi)
                hv[u] = *reinterpret_cast<const unsigned int*>(
                    xb + (size_t)(pk[u] & 0x1FFFFu) * DD + lane * 2);
        }
#pragma unroll
        for (int u = 0; u < 8; ++u) {
            if (sl[u] >= lo && sl[u] < hi) {
                unsigned int rel = sl[u] - lo;
                float sc = __builtin_amdgcn_rcpf((float)(pk[u] >> 17));
                union { unsigned int u32; float f; } l_, h_;
                l_.u32 = hv[u] << 16; h_.u32 = hv[u] & 0xffff0000u;
                float flo = l_.f * sc, fhi = h_.f * sc;
                unsigned int w32;
                asm volatile("v_cvt_pk_bf16_f32 %0, %1, %2"
                             : "=v"(w32) : "v"(flo), "v"(fhi));
                __builtin_nontemporal_store(w32,
                    reinterpret_cast<unsigned int*>(y + (size_t)rel * DD + lane * 2));
            }
        }
    }
}

// Aggregate layer: block = 512 thr = 8 waves = 16 dst nodes (2/wave).
// Phase 1: sequential y-segment read (node-ordered CSR -> one long stream),
//          run-flush per relation (sum; scale pre-applied) into swizzled LDS;
//          root x at slice 8.
// Phase 2: out[16][128] = xagg @ Wcat^T via MFMA, +bias, relu.
// mode 1: bf16 store (next layer input); mode 2: f32 store (final output).
__global__ __launch_bounds__(512) void agg_k(const unsigned short* __restrict__ xb,
                                             const unsigned short* __restrict__ wcat,
                                             const float* __restrict__ bias,
                                             const unsigned char* __restrict__ recD,
                                             const unsigned int* __restrict__ segBeg,
                                             const unsigned int* __restrict__ segLen,
                                             const unsigned short* __restrict__ y,
                                             const unsigned int* __restrict__ cOff,
                                             int c, int nodeLo,
                                             unsigned short* __restrict__ obf,
                                             float* __restrict__ of32,
                                             int mode) {
    __shared__ unsigned short ldsx[16 * KCAT];      // 36,864 B
    const unsigned int chunkOff = cOff[c];
    const int wave = threadIdx.x >> 6;              // 0..7
    const int lane = threadIdx.x & 63;
    const int c16  = lane & 15;
    const int grp  = lane >> 4;
    const int lq   = lane >> 2;
    const int lm   = lane & 3;
    const int blk  = blockIdx.x;
    unsigned int* lds32 = reinterpret_cast<unsigned int*>(ldsx);

    // ---------- phase 1: sequential segment read + run-flush ----------
    for (int nl = 0; nl < 2; ++nl) {
        const int row  = wave * 2 + nl;             // LDS row 0..15
        const int node = nodeLo + blk * 16 + row;
        const int sbase = row * (KCAT / 2);         // u32 units per row
        const int xorv = row & 7;

        // zero relation slices; write root slice (m=8)
#pragma unroll
        for (int r = 0; r < 8; ++r)
            lds32[sbase + (((r * 16 + lq) ^ xorv) << 2) + lm] = 0u;
        lds32[sbase + (((128 + lq) ^ xorv) << 2) + lm] =
            *reinterpret_cast<const unsigned int*>(xb + (size_t)node * DD + lane * 2);

        const unsigned int beg = segBeg[node];
        const unsigned int len = segLen[node];
        const unsigned char* rp = recD + beg;
        const unsigned short* yb = y + (size_t)(beg - chunkOff) * DD;

        float ax = 0.f, ay = 0.f;
        unsigned int rc = 15u;
        for (unsigned int j = 0; j < len; j += 8) {
            int n = (int)(len - j); if (n > 8) n = 8;
            unsigned int hv[8]; unsigned char rr[8];
#pragma unroll
            for (int u = 0; u < 8; ++u)
                if (u < n) {
                    rr[u] = rp[j + u];
                    hv[u] = *reinterpret_cast<const unsigned int*>(
                        yb + (size_t)(j + u) * DD + lane * 2);
                }
#pragma unroll
            for (int u = 0; u < 8; ++u)
                if (u < n) {
                    unsigned int r = rr[u];
                    if (r != rc) {
                        if (rc < 8u) {
                            unsigned int w32 = ((unsigned int)f2bf(ay) << 16)
                                             | (unsigned int)f2bf(ax);
                            lds32[sbase + ((((int)rc * 16 + lq) ^ xorv) << 2) + lm] = w32;
                        }
                        rc = r; ax = 0.f; ay = 0.f;
                    }
                    union { unsigned int u32; float f; } lo, hi;
                    lo.u32 = hv[u] << 16; hi.u32 = hv[u] & 0xffff0000u;
                    ax += lo.f; ay += hi.f;
                }
        }
        if (rc < 8u) {
            unsigned int w32 = ((unsigned int)f2bf(ay) << 16)
                             | (unsigned int)f2bf(ax);
            lds32[sbase + ((((int)rc * 16 + lq) ^ xorv) << 2) + lm] = w32;
        }
    }
    __syncthreads();

    // ---------- phase 2: MFMA out = xagg @ Wcat^T (wave w -> col tile w) ----------
    f32x4 acc = f32x4{0.f, 0.f, 0.f, 0.f};
    const unsigned short* arow = wcat + (size_t)(wave * 16 + c16) * KCAT;
#pragma unroll
    for (int kk = 0; kk < KCAT / 32; ++kk) {        // 36 k-steps
        int slot = (kk * 4 + grp) ^ (c16 & 7);
        bf16x8 b = *reinterpret_cast<const bf16x8*>(&ldsx[c16 * KCAT + slot * 8]);
        bf16x8 a = *reinterpret_cast<const bf16x8*>(arow + kk * 32 + grp * 8);
        acc = __builtin_amdgcn_mfma_f32_16x16x32_bf16(a, b, acc, 0, 0, 0);
    }

    // ---------- epilogue: +bias, relu, store ----------
    const int node = nodeLo + blk * 16 + c16;
    const int od = wave * 16 + grp * 4;
    const float4 bv = *reinterpret_cast<const float4*>(bias + od);
    float o0 = fmaxf(acc[0] + bv.x, 0.f);
    float o1 = fmaxf(acc[1] + bv.y, 0.f);
    float o2 = fmaxf(acc[2] + bv.z, 0.f);
    float o3 = fmaxf(acc[3] + bv.w, 0.f);
    if (mode == 1) {
        union { unsigned short s[4]; uint2 v; } pko;
        pko.s[0] = f2bf(o0); pko.s[1] = f2bf(o1);
        pko.s[2] = f2bf(o2); pko.s[3] = f2bf(o3);
        *reinterpret_cast<uint2*>(obf + (size_t)node * DD + od) = pko.v;
    } else {
        *reinterpret_cast<float4*>(of32 + (size_t)node * DD + od)
            = make_float4(o0, o1, o2, o3);
    }
}

extern "C" void kernel_launch(void* const* d_in, const int* in_sizes, int n_in,
                              void* d_out, int out_size, void* d_ws, size_t ws_size,
                              hipStream_t stream) {
    const float* x  = (const float*)d_in[0];
    const int*   ei = (const int*)d_in[1];
    const int*   et = (const int*)d_in[2];
    const float* W1 = (const float*)d_in[3];
    const float* r1 = (const float*)d_in[4];
    const float* b1 = (const float*)d_in[5];
    const float* W2 = (const float*)d_in[6];
    const float* r2 = (const float*)d_in[7];
    const float* b2 = (const float*)d_in[8];
    float* out = (float*)d_out;

    // ---- fixed workspace layout (~70 MB) ----
    char* ws = (char*)d_ws;
    unsigned int*   deg8   = (unsigned int*)ws;                   // NN*8 u32
    unsigned int*   srcCnt = deg8 + (size_t)NN * 8;               // NN u32 (zeroed w/ deg8)
    unsigned int*   posS   = srcCnt + NN;                         // NN u32
    unsigned int*   pos8   = posS + NN;                           // NN*8 u32
    unsigned int*   segBeg = pos8 + (size_t)NN * 8;               // NN u32
    unsigned int*   segLen = segBeg + NN;                         // NN u32
    unsigned int*   locD   = segLen + NN;                         // NN u32
    unsigned int*   locS   = locD + NN;                           // NN u32
    unsigned int*   blkD   = locS + NN;                           // 512 u32
    unsigned int*   blkS   = blkD + 512;                          // 512 u32
    unsigned int*   cOff   = blkS + 512;                          // 64 u32
    unsigned int*   recA   = cOff + 64;                           // NE u32
    unsigned int*   recB   = recA + NE;                           // NE u32
    unsigned char*  recD   = (unsigned char*)(recB + NE);         // NE B
    unsigned short* wc1    = (unsigned short*)(recD + NE);        // 294,912 B
    unsigned short* wc2    = wc1 + DD * KCAT;
    unsigned short* xbuf   = wc2 + DD * KCAT;                     // 25.6 MB
    unsigned short* xbuf2  = xbuf + (size_t)NN * DD;              // 25.6 MB
    size_t fixedEnd = (size_t)((char*)(xbuf2 + (size_t)NN * DD) - ws);
    fixedEnd = (fixedEnd + 255) & ~(size_t)255;

    // ---- adaptive y sizing (CAP rows of 256 B) ----
    if (ws_size < fixedEnd + 1024) return;                        // loud failure
    size_t avail = ws_size - fixedEnd - 256;
    int nch; unsigned int CAP;
    if (avail >= (size_t)NE * 256) { nch = 1; CAP = NE; }
    else {
        nch = 2;
        CAP = (unsigned int)(avail / 256);
        if (CAP < 530000u) return;                                // loud failure
    }
    unsigned short* y = (unsigned short*)(ws + fixedEnd);         // CAP*256 B

    const int* srcv = ei;
    const int* dstv = ei + NE;

    hipMemsetAsync(deg8, 0, (size_t)NN * 9 * 4, stream);          // deg8 + srcCnt
    cvt_x_k<<<(NN * DD / 4) / 256, 256, 0, stream>>>(x, xbuf, NN * DD / 4);
    cvt_w_k<<<(2 * DD * KCAT) / 256, 256, 0, stream>>>(W1, r1, W2, r2, wc1, wc2);
    hist_k<<<(NE + 255) / 256, 256, 0, stream>>>(srcv, dstv, et, deg8, srcCnt);
    scanA_k<<<SCAN_BLKS, 256, 0, stream>>>(deg8, srcCnt, locD, locS, blkD, blkS);
    scanB_k<<<1, 512, 0, stream>>>(blkD, blkS, cOff, nch);
    scanC_k<<<SCAN_BLKS, 256, 0, stream>>>(deg8, locD, locS, blkD, blkS,
                                           pos8, posS, segBeg, segLen);
    fill_k<<<(NE + 255) / 256, 256, 0, stream>>>(srcv, dstv, et, deg8, pos8, posS,
                                                 recA, recB, recD);

    for (int layer = 0; layer < 2; ++layer) {
        const unsigned short* in = layer ? xbuf2 : xbuf;
        const unsigned short* wc = layer ? wc2 : wc1;
        const float* bb = layer ? b2 : b1;
        for (int c = 0; c < nch; ++c) {
            const int nodeLo = (c == 0) ? 0 : CHB;
            const int nodes  = (nch == 1) ? NN : ((c == 0) ? CHB : NN - CHB);
            spread_k<<<625, 512, 0, stream>>>(in, recA, recB, y, cOff, c);
            agg_k<<<nodes / 16, 512, 0, stream>>>(in, wc, bb, recD, segBeg, segLen,
                                                  y, cOff, c, nodeLo,
                                                  layer ? (unsigned short*)nullptr : xbuf2,
                                                  layer ? out : (float*)nullptr,
                                                  layer ? 2 : 1);
        }
    }
}